// Round 2
// baseline (385.780 us; speedup 1.0000x reference)
//
#include <hip/hip_runtime.h>
#include <hip/hip_bf16.h>
#include <math.h>

#define NBINS 15
#define NB1 2048          // stage-1 blocks (8 per CU)
#define BLK 256           // threads per block (4 waves)

// Stage 1: one wave per row. Direct exp (no max subtraction -> short critical
// path): sum-of-exp accumulates as loads land; single fused butterfly reduces
// (sum, max, argmax) together. Per-block bin sums in LDS, partials written
// TRANSPOSED ([45][NB1]) for coalesced stage-2 reads.
__global__ __launch_bounds__(BLK, 4) void ece_rows_kernel(
    const float* __restrict__ logits,
    const int*   __restrict__ labels,
    float* __restrict__ partials,   // [3*NBINS][NB1]
    int N, int C)
{
    __shared__ float sb[3 * NBINS];  // cnt[15], conf_sum[15], acc_sum[15]

    const int t = threadIdx.x;
    if (t < 3 * NBINS) sb[t] = 0.0f;
    __syncthreads();

    const int lane   = t & 63;
    const int wave   = (blockIdx.x * BLK + t) >> 6;
    const int nwaves = (NB1 * BLK) >> 6;
    const int nvec   = (C + 3) >> 2;   // 250 float4 per row for C=1000

    for (int row = wave; row < N; row += nwaves) {
        const float4* __restrict__ rp = (const float4*)(logits + (size_t)row * C);

        float4 v[4];
        #pragma unroll
        for (int k = 0; k < 4; ++k) {
            int idx = lane + 64 * k;
            v[k] = (idx < nvec) ? rp[idx]
                                : make_float4(-INFINITY, -INFINITY, -INFINITY, -INFINITY);
        }

        // lane-local: 4 independent exp accumulators + max/argmax (first occurrence)
        float s0 = 0.f, s1 = 0.f, s2 = 0.f, s3 = 0.f;
        float m = -INFINITY;
        int   am = 0;
        #pragma unroll
        for (int k = 0; k < 4; ++k) {
            const float* e = (const float*)&v[k];
            int col = (lane + 64 * k) * 4;
            s0 += __expf(e[0]);          // exp(-inf)=0 handles the tail
            s1 += __expf(e[1]);
            s2 += __expf(e[2]);
            s3 += __expf(e[3]);
            #pragma unroll
            for (int j = 0; j < 4; ++j) {
                float x = e[j];
                if (x > m) { m = x; am = col + j; }
            }
        }
        float s = (s0 + s1) + (s2 + s3);

        // single fused butterfly: sum, max, argmax (min column on tie)
        #pragma unroll
        for (int off = 32; off; off >>= 1) {
            float m2  = __shfl_xor(m,  off, 64);
            float sv  = __shfl_xor(s,  off, 64);
            int   am2 = __shfl_xor(am, off, 64);
            s += sv;
            if (m2 > m || (m2 == m && am2 < am)) { m = m2; am = am2; }
        }

        if (lane == 0) {
            float conf = __expf(m) / s;        // == exp(m-m)/sum(exp(x-m)) exactly in math
            float acc  = (am == labels[row]) ? 1.0f : 0.0f;
            int b = 0;
            #pragma unroll
            for (int k = 1; k < NBINS; ++k)
                b += (conf > (float)k * (1.0f / 15.0f)) ? 1 : 0;
            atomicAdd(&sb[b],             1.0f);
            atomicAdd(&sb[NBINS + b],     conf);
            atomicAdd(&sb[2 * NBINS + b], acc);
        }
    }

    __syncthreads();
    if (t < 3 * NBINS)
        partials[(size_t)t * NB1 + blockIdx.x] = sb[t];
}

// Stage 2: reduce [45][NB1] partials in double, compute ece & acc.
__global__ __launch_bounds__(1024) void ece_final_kernel(
    const float* __restrict__ partials, float* __restrict__ out, int N)
{
    __shared__ double red[3 * NBINS][16];
    const int t = threadIdx.x;
    const int c = t >> 4;     // component 0..63 (use 0..44)
    const int sub = t & 15;

    if (c < 3 * NBINS) {
        double a = 0.0;
        for (int b = sub; b < NB1; b += 16)          // coalesced within 16-thread group
            a += (double)partials[(size_t)c * NB1 + b];
        red[c][sub] = a;
    }
    __syncthreads();
    if (t < 3 * NBINS) {
        double ssum = 0.0;
        #pragma unroll
        for (int i = 0; i < 16; ++i) ssum += red[t][i];
        red[t][0] = ssum;
    }
    __syncthreads();
    if (t == 0) {
        double ece = 0.0, acc = 0.0;
        const double n = (double)N;
        for (int k = 0; k < NBINS; ++k) {
            double cnt = red[k][0];
            double cs  = red[NBINS + k][0];
            double as  = red[2 * NBINS + k][0];
            if (cnt > 0.0) {
                double avg_conf = cs / cnt;
                double avg_acc  = as / cnt;
                double prop     = cnt / n;
                ece += fabs(avg_conf - avg_acc) * prop;
                acc += avg_acc * prop;
            }
        }
        out[0] = (float)(ece * 100.0);
        out[1] = (float)(acc * 100.0);
    }
}

extern "C" void kernel_launch(void* const* d_in, const int* in_sizes, int n_in,
                              void* d_out, int out_size, void* d_ws, size_t ws_size,
                              hipStream_t stream) {
    const float* logits = (const float*)d_in[0];
    const int*   labels = (const int*)d_in[1];
    float* out = (float*)d_out;

    const int N = in_sizes[1];            // 65536
    const int C = in_sizes[0] / N;        // 1000

    float* partials = (float*)d_ws;       // 45 * NB1 floats = 368,640 B

    ece_rows_kernel<<<NB1, BLK, 0, stream>>>(logits, labels, partials, N, C);
    ece_final_kernel<<<1, 1024, 0, stream>>>(partials, out, N);
}